// Round 2
// baseline (371.064 us; speedup 1.0000x reference)
//
#include <hip/hip_runtime.h>
#include <hip/hip_bf16.h>

#define N_NODES 50000
#define N_EDGES 800000
#define HEADS 4
#define OUT_CH 32
#define FDIM (HEADS * OUT_CH)   // 128

// ---------- Pass 1: per-node dot products ----------
// ab[n*8 + h*2 + 0] = dot(x[n,h,:], w[:32])   (a, used by destination i)
// ab[n*8 + h*2 + 1] = dot(x[n,h,:], w[32:])   (b, used by source j)
__global__ void node_dots_kernel(const float* __restrict__ x,
                                 const float* __restrict__ w,
                                 float* __restrict__ ab,
                                 int n_nodes) {
    int gid = blockIdx.x * blockDim.x + threadIdx.x;
    int node = gid >> 7;
    int t = threadIdx.x & 127;
    if (node >= n_nodes) return;
    int h = t >> 5;
    int c = t & 31;

    float xv = x[node * FDIM + t];
    float pa = xv * w[c];
    float pb = xv * w[OUT_CH + c];
    #pragma unroll
    for (int m = 16; m >= 1; m >>= 1) {
        pa += __shfl_xor(pa, m);
        pb += __shfl_xor(pb, m);
    }
    if (c == 0) {
        ab[node * 8 + h * 2 + 0] = pa;
        ab[node * 8 + h * 2 + 1] = pb;
    }
}

// ---------- CSR build ----------
__global__ void hist_kernel(const int* __restrict__ ei, int* __restrict__ cnt,
                            int n_edges) {
    int e = blockIdx.x * blockDim.x + threadIdx.x;
    if (e < n_edges) atomicAdd(&cnt[ei[e]], 1);
}

// single-block exclusive scan: offs[i] = start of node i; offs[n] = total.
// Also duplicates into cursor[] for the scatter pass.
__global__ __launch_bounds__(1024) void scan_kernel(const int* __restrict__ cnt,
                                                    int* __restrict__ offs,
                                                    int* __restrict__ cursor,
                                                    int n) {
    const int T = 1024;
    int tid = threadIdx.x;
    int per = (n + T - 1) / T;
    int beg = tid * per;
    int end = beg + per; if (end > n) end = n;
    int s = 0;
    if (beg < n) for (int k = beg; k < end; ++k) s += cnt[k];
    __shared__ int lds[T];
    lds[tid] = s;
    __syncthreads();
    for (int d = 1; d < T; d <<= 1) {
        int t = (tid >= d) ? lds[tid - d] : 0;
        __syncthreads();
        lds[tid] += t;
        __syncthreads();
    }
    int excl = lds[tid] - s;
    if (beg < n) {
        for (int k = beg; k < end; ++k) {
            offs[k] = excl;
            cursor[k] = excl;
            excl += cnt[k];
        }
    }
    if (tid == T - 1) offs[n] = lds[T - 1];
}

// scatter (j, weight) records into destination-sorted order
__global__ void csr_scatter_kernel(const int* __restrict__ ei,
                                   const int* __restrict__ ej,
                                   const float* __restrict__ weights,
                                   int* __restrict__ cursor,
                                   int* __restrict__ jsort,
                                   float* __restrict__ wsort,
                                   int n_edges) {
    int e = blockIdx.x * blockDim.x + threadIdx.x;
    if (e >= n_edges) return;
    int i = ei[e];
    int p = atomicAdd(&cursor[i], 1);
    jsort[p] = ej[e];
    wsort[p] = weights[e];
}

// ---------- Pass 2: gather-accumulate, no output atomics ----------
__global__ void gather_kernel(const float* __restrict__ x,
                              const float* __restrict__ ab,
                              const int* __restrict__ offs,
                              const int* __restrict__ jsort,
                              const float* __restrict__ wsort,
                              float* __restrict__ out,
                              int n_nodes) {
    int gid = blockIdx.x * blockDim.x + threadIdx.x;
    int node = gid >> 7;          // 128 threads per node
    int t = threadIdx.x & 127;
    if (node >= n_nodes) return;
    int h = t >> 5;

    int start = offs[node];
    int end = offs[node + 1];
    float a_i = ab[node * 8 + h * 2 + 0];
    float acc = 0.0f;
    for (int k = start; k < end; ++k) {
        int j = jsort[k];
        float b_j = ab[j * 8 + h * 2 + 1];
        float beta = wsort[k] / (1.0f + __expf(-(a_i + b_j)));
        acc += x[j * FDIM + t] * beta;
    }
    out[node * FDIM + t] = acc;
}

// ---------- fallback: original atomic scatter (if ws too small) ----------
__global__ void edge_scatter_kernel(const float* __restrict__ x,
                                    const int* __restrict__ ei_arr,
                                    const int* __restrict__ ej_arr,
                                    const float* __restrict__ weights,
                                    const float* __restrict__ ab,
                                    float* __restrict__ out,
                                    int n_edges) {
    int gid = blockIdx.x * blockDim.x + threadIdx.x;
    int e = gid >> 7;
    int t = threadIdx.x & 127;
    if (e >= n_edges) return;
    int h = t >> 5;
    int i = ei_arr[e];
    int j = ej_arr[e];
    float alpha = ab[i * 8 + h * 2 + 0] + ab[j * 8 + h * 2 + 1];
    float beta = weights[e] / (1.0f + __expf(-alpha));
    atomicAdd(&out[i * FDIM + t], x[j * FDIM + t] * beta);
}

extern "C" void kernel_launch(void* const* d_in, const int* in_sizes, int n_in,
                              void* d_out, int out_size, void* d_ws, size_t ws_size,
                              hipStream_t stream) {
    const float* x       = (const float*)d_in[0];   // (N_NODES, 128) f32
    const int*   eidx    = (const int*)d_in[1];     // (2, N_EDGES) int
    const float* weights = (const float*)d_in[2];   // (N_EDGES,) f32
    const float* w       = (const float*)d_in[3];   // (64,) f32
    float* out = (float*)d_out;

    const int* ei_arr = eidx;
    const int* ej_arr = eidx + N_EDGES;

    // workspace layout (all 4-byte elements)
    float* ab     = (float*)d_ws;                    // 400000
    int*   cnt    = (int*)d_ws + 400000;             // 50000
    int*   offs   = cnt + N_NODES;                   // 50001
    int*   cursor = offs + N_NODES + 1;              // 50000
    int*   jsort  = cursor + N_NODES;                // 800000
    float* wsort  = (float*)(jsort + N_EDGES);       // 800000
    size_t need = (size_t)(400000 + N_NODES * 3 + 1 + N_EDGES * 2) * 4;

    // Pass 1: per-node dots (needed by both paths)
    {
        int threads_total = N_NODES * FDIM;
        int block = 256;
        int grid = (threads_total + block - 1) / block;
        node_dots_kernel<<<grid, block, 0, stream>>>(x, w, ab, N_NODES);
    }

    if (ws_size < need) {
        // fallback: atomic scatter path
        hipMemsetAsync(d_out, 0, (size_t)out_size * sizeof(float), stream);
        long long threads_total = (long long)N_EDGES * FDIM;
        int block = 256;
        long long grid = (threads_total + block - 1) / block;
        edge_scatter_kernel<<<(int)grid, block, 0, stream>>>(
            x, ei_arr, ej_arr, weights, ab, out, N_EDGES);
        return;
    }

    // CSR build
    hipMemsetAsync(cnt, 0, (size_t)N_NODES * sizeof(int), stream);
    {
        int block = 256;
        int grid = (N_EDGES + block - 1) / block;
        hist_kernel<<<grid, block, 0, stream>>>(ei_arr, cnt, N_EDGES);
        scan_kernel<<<1, 1024, 0, stream>>>(cnt, offs, cursor, N_NODES);
        csr_scatter_kernel<<<grid, block, 0, stream>>>(
            ei_arr, ej_arr, weights, cursor, jsort, wsort, N_EDGES);
    }

    // gather-accumulate (writes every output element exactly once)
    {
        int threads_total = N_NODES * FDIM;
        int block = 256;
        int grid = (threads_total + block - 1) / block;
        gather_kernel<<<grid, block, 0, stream>>>(
            x, ab, offs, jsort, wsort, out, N_NODES);
    }
}

// Round 3
// 158.215 us; speedup vs baseline: 2.3453x; 2.3453x over previous
//
#include <hip/hip_runtime.h>
#include <hip/hip_bf16.h>

#define N_NODES 50000
#define N_EDGES 800000
#define HEADS 4
#define OUT_CH 32
#define FDIM (HEADS * OUT_CH)   // 128

// ============================================================================
// v2 path: float4 everywhere, beta precomputed per edge in CSR build
// ============================================================================

// A[n][4] = dot(x[n,h,:], w[:32]);  B[n][4] = dot(x[n,h,:], w[32:])
// 32 threads per node, float4 loads, 3-shuffle reduce over 8 lanes.
__global__ void node_dots4_kernel(const float4* __restrict__ x4,
                                  const float* __restrict__ w,
                                  float* __restrict__ Af,
                                  float* __restrict__ Bf) {
    int gid = blockIdx.x * blockDim.x + threadIdx.x;
    int node = gid >> 5;
    int t = threadIdx.x & 31;
    int h = t >> 3;
    int q8 = t & 7;

    float4 xv = x4[node * 32 + t];
    const float4* w4 = (const float4*)w;
    float4 wi = w4[q8];
    float4 wj = w4[8 + q8];
    float pa = xv.x * wi.x + xv.y * wi.y + xv.z * wi.z + xv.w * wi.w;
    float pb = xv.x * wj.x + xv.y * wj.y + xv.z * wj.z + xv.w * wj.w;
    #pragma unroll
    for (int m = 4; m >= 1; m >>= 1) {
        pa += __shfl_xor(pa, m);
        pb += __shfl_xor(pb, m);
    }
    if (q8 == 0) {
        Af[node * 4 + h] = pa;
        Bf[node * 4 + h] = pb;
    }
}

__global__ void hist_kernel(const int* __restrict__ ei, int* __restrict__ cnt,
                            int n_edges) {
    int e = blockIdx.x * blockDim.x + threadIdx.x;
    if (e < n_edges) atomicAdd(&cnt[ei[e]], 1);
}

// multi-block scan: pass 1 — block-local exclusive scan + block sums
__global__ void scan1_kernel(const int* __restrict__ cnt, int* __restrict__ offs,
                             int* __restrict__ bsums, int n) {
    __shared__ int lds[256];
    int i = blockIdx.x * 256 + threadIdx.x;
    int v = (i < n) ? cnt[i] : 0;
    lds[threadIdx.x] = v;
    __syncthreads();
    for (int d = 1; d < 256; d <<= 1) {
        int t = (threadIdx.x >= d) ? lds[threadIdx.x - d] : 0;
        __syncthreads();
        lds[threadIdx.x] += t;
        __syncthreads();
    }
    if (i < n) offs[i] = lds[threadIdx.x] - v;
    if (threadIdx.x == 255) bsums[blockIdx.x] = lds[255];
}

// pass 2 — exclusive scan of block sums (<=256 of them) + total
__global__ void scan2_kernel(int* __restrict__ bsums, int* __restrict__ offs_n,
                             int nb) {
    __shared__ int lds[256];
    int v = (threadIdx.x < nb) ? bsums[threadIdx.x] : 0;
    lds[threadIdx.x] = v;
    __syncthreads();
    for (int d = 1; d < 256; d <<= 1) {
        int t = (threadIdx.x >= d) ? lds[threadIdx.x - d] : 0;
        __syncthreads();
        lds[threadIdx.x] += t;
        __syncthreads();
    }
    if (threadIdx.x < nb) bsums[threadIdx.x] = lds[threadIdx.x] - v;
    if (threadIdx.x == 255) *offs_n = lds[255];
}

// pass 3 — add block offsets, duplicate into cursor
__global__ void scan3_kernel(int* __restrict__ offs, int* __restrict__ cursor,
                             const int* __restrict__ bsums, int n) {
    int i = blockIdx.x * 256 + threadIdx.x;
    if (i < n) {
        int o = offs[i] + bsums[blockIdx.x];
        offs[i] = o;
        cursor[i] = o;
    }
}

// per-edge: compute beta[4] = w_e * sigmoid(A_i + B_j), scatter (j, beta)
__global__ void csr_scatter4_kernel(const int* __restrict__ ei,
                                    const int* __restrict__ ej,
                                    const float* __restrict__ weights,
                                    const float4* __restrict__ A4,
                                    const float4* __restrict__ B4,
                                    int* __restrict__ cursor,
                                    int* __restrict__ jsort,
                                    float4* __restrict__ beta4,
                                    int n_edges) {
    int e = blockIdx.x * blockDim.x + threadIdx.x;
    if (e >= n_edges) return;
    int i = ei[e];
    int j = ej[e];
    float we = weights[e];
    float4 ai = A4[i];
    float4 bj = B4[j];
    float4 bt;
    bt.x = we / (1.0f + __expf(-(ai.x + bj.x)));
    bt.y = we / (1.0f + __expf(-(ai.y + bj.y)));
    bt.z = we / (1.0f + __expf(-(ai.z + bj.z)));
    bt.w = we / (1.0f + __expf(-(ai.w + bj.w)));
    int p = atomicAdd(&cursor[i], 1);
    jsort[p] = j;
    beta4[p] = bt;
}

// gather-accumulate: 32 threads per node, float4 per thread, no transcendentals
__global__ void gather4_kernel(const float4* __restrict__ x4,
                               const int* __restrict__ offs,
                               const int* __restrict__ jsort,
                               const float* __restrict__ betaf,
                               float4* __restrict__ out4) {
    int gid = blockIdx.x * blockDim.x + threadIdx.x;
    int node = gid >> 5;
    int t = threadIdx.x & 31;
    int h = t >> 3;

    int start = offs[node];
    int end = offs[node + 1];
    float4 acc = make_float4(0.f, 0.f, 0.f, 0.f);
    #pragma unroll 4
    for (int k = start; k < end; ++k) {
        int j = jsort[k];
        float beta = betaf[k * 4 + h];
        float4 xv = x4[j * 32 + t];
        acc.x += xv.x * beta;
        acc.y += xv.y * beta;
        acc.z += xv.z * beta;
        acc.w += xv.w * beta;
    }
    out4[node * 32 + t] = acc;
}

// ============================================================================
// v1 fallback path (verified round-2 kernels)
// ============================================================================

__global__ void node_dots_kernel(const float* __restrict__ x,
                                 const float* __restrict__ w,
                                 float* __restrict__ ab,
                                 int n_nodes) {
    int gid = blockIdx.x * blockDim.x + threadIdx.x;
    int node = gid >> 7;
    int t = threadIdx.x & 127;
    if (node >= n_nodes) return;
    int h = t >> 5;
    int c = t & 31;
    float xv = x[node * FDIM + t];
    float pa = xv * w[c];
    float pb = xv * w[OUT_CH + c];
    #pragma unroll
    for (int m = 16; m >= 1; m >>= 1) {
        pa += __shfl_xor(pa, m);
        pb += __shfl_xor(pb, m);
    }
    if (c == 0) {
        ab[node * 8 + h * 2 + 0] = pa;
        ab[node * 8 + h * 2 + 1] = pb;
    }
}

__global__ __launch_bounds__(1024) void scan_kernel(const int* __restrict__ cnt,
                                                    int* __restrict__ offs,
                                                    int* __restrict__ cursor,
                                                    int n) {
    const int T = 1024;
    int tid = threadIdx.x;
    int per = (n + T - 1) / T;
    int beg = tid * per;
    int end = beg + per; if (end > n) end = n;
    int s = 0;
    if (beg < n) for (int k = beg; k < end; ++k) s += cnt[k];
    __shared__ int lds[T];
    lds[tid] = s;
    __syncthreads();
    for (int d = 1; d < T; d <<= 1) {
        int t = (tid >= d) ? lds[tid - d] : 0;
        __syncthreads();
        lds[tid] += t;
        __syncthreads();
    }
    int excl = lds[tid] - s;
    if (beg < n) {
        for (int k = beg; k < end; ++k) {
            offs[k] = excl;
            cursor[k] = excl;
            excl += cnt[k];
        }
    }
    if (tid == T - 1) offs[n] = lds[T - 1];
}

__global__ void csr_scatter_kernel(const int* __restrict__ ei,
                                   const int* __restrict__ ej,
                                   const float* __restrict__ weights,
                                   int* __restrict__ cursor,
                                   int* __restrict__ jsort,
                                   float* __restrict__ wsort,
                                   int n_edges) {
    int e = blockIdx.x * blockDim.x + threadIdx.x;
    if (e >= n_edges) return;
    int i = ei[e];
    int p = atomicAdd(&cursor[i], 1);
    jsort[p] = ej[e];
    wsort[p] = weights[e];
}

__global__ void gather_kernel(const float* __restrict__ x,
                              const float* __restrict__ ab,
                              const int* __restrict__ offs,
                              const int* __restrict__ jsort,
                              const float* __restrict__ wsort,
                              float* __restrict__ out,
                              int n_nodes) {
    int gid = blockIdx.x * blockDim.x + threadIdx.x;
    int node = gid >> 7;
    int t = threadIdx.x & 127;
    if (node >= n_nodes) return;
    int h = t >> 5;
    int start = offs[node];
    int end = offs[node + 1];
    float a_i = ab[node * 8 + h * 2 + 0];
    float acc = 0.0f;
    for (int k = start; k < end; ++k) {
        int j = jsort[k];
        float b_j = ab[j * 8 + h * 2 + 1];
        float beta = wsort[k] / (1.0f + __expf(-(a_i + b_j)));
        acc += x[j * FDIM + t] * beta;
    }
    out[node * FDIM + t] = acc;
}

__global__ void edge_scatter_kernel(const float* __restrict__ x,
                                    const int* __restrict__ ei_arr,
                                    const int* __restrict__ ej_arr,
                                    const float* __restrict__ weights,
                                    const float* __restrict__ ab,
                                    float* __restrict__ out,
                                    int n_edges) {
    int gid = blockIdx.x * blockDim.x + threadIdx.x;
    int e = gid >> 7;
    int t = threadIdx.x & 127;
    if (e >= n_edges) return;
    int h = t >> 5;
    int i = ei_arr[e];
    int j = ej_arr[e];
    float alpha = ab[i * 8 + h * 2 + 0] + ab[j * 8 + h * 2 + 1];
    float beta = weights[e] / (1.0f + __expf(-alpha));
    atomicAdd(&out[i * FDIM + t], x[j * FDIM + t] * beta);
}

// ============================================================================

extern "C" void kernel_launch(void* const* d_in, const int* in_sizes, int n_in,
                              void* d_out, int out_size, void* d_ws, size_t ws_size,
                              hipStream_t stream) {
    const float* x       = (const float*)d_in[0];
    const int*   eidx    = (const int*)d_in[1];
    const float* weights = (const float*)d_in[2];
    const float* w       = (const float*)d_in[3];
    float* out = (float*)d_out;

    const int* ei_arr = eidx;
    const int* ej_arr = eidx + N_EDGES;

    // ---- v2 workspace layout (floats/ints, 4B units) ----
    // A: 200000 | B: 200000 | beta4: 3200000 | jsort: 800000 |
    // cnt: 50000 | offs: 50001 | cursor: 50000 | bsums: 256
    float* Af     = (float*)d_ws;                       // node*4+h
    float* Bf     = Af + N_NODES * 4;
    float* betaf  = Bf + N_NODES * 4;                   // float4-aligned
    int*   jsort2 = (int*)(betaf + (size_t)N_EDGES * 4);
    int*   cnt2   = jsort2 + N_EDGES;
    int*   offs2  = cnt2 + N_NODES;
    int*   cur2   = offs2 + N_NODES + 1;
    int*   bsums  = cur2 + N_NODES;
    size_t need_v2 = (size_t)(N_NODES * 8 + N_EDGES * 5 + N_NODES * 3 + 1 + 256) * 4;

    const int NB = (N_NODES + 255) / 256;  // 196 scan blocks

    if (ws_size >= need_v2) {
        hipMemsetAsync(cnt2, 0, (size_t)N_NODES * sizeof(int), stream);
        {   // per-node dots, float4
            int grid = (N_NODES * 32 + 255) / 256;
            node_dots4_kernel<<<grid, 256, 0, stream>>>(
                (const float4*)x, w, Af, Bf);
        }
        {   // histogram of destinations
            int grid = (N_EDGES + 255) / 256;
            hist_kernel<<<grid, 256, 0, stream>>>(ei_arr, cnt2, N_EDGES);
        }
        scan1_kernel<<<NB, 256, 0, stream>>>(cnt2, offs2, bsums, N_NODES);
        scan2_kernel<<<1, 256, 0, stream>>>(bsums, offs2 + N_NODES, NB);
        scan3_kernel<<<NB, 256, 0, stream>>>(offs2, cur2, bsums, N_NODES);
        {   // per-edge beta + scatter
            int grid = (N_EDGES + 255) / 256;
            csr_scatter4_kernel<<<grid, 256, 0, stream>>>(
                ei_arr, ej_arr, weights, (const float4*)Af, (const float4*)Bf,
                cur2, jsort2, (float4*)betaf, N_EDGES);
        }
        {   // gather, float4, no transcendentals
            int grid = (N_NODES * 32 + 255) / 256;
            gather4_kernel<<<grid, 256, 0, stream>>>(
                (const float4*)x, offs2, jsort2, betaf, (float4*)out);
        }
        return;
    }

    // ---- v1 fallback (round-2 verified) ----
    float* ab     = (float*)d_ws;
    int*   cnt    = (int*)d_ws + 400000;
    int*   offs   = cnt + N_NODES;
    int*   cursor = offs + N_NODES + 1;
    int*   jsort  = cursor + N_NODES;
    float* wsort  = (float*)(jsort + N_EDGES);
    size_t need_v1 = (size_t)(400000 + N_NODES * 3 + 1 + N_EDGES * 2) * 4;

    {
        int grid = (N_NODES * FDIM + 255) / 256;
        node_dots_kernel<<<grid, 256, 0, stream>>>(x, w, ab, N_NODES);
    }
    if (ws_size < need_v1) {
        hipMemsetAsync(d_out, 0, (size_t)out_size * sizeof(float), stream);
        long long threads_total = (long long)N_EDGES * FDIM;
        long long grid = (threads_total + 255) / 256;
        edge_scatter_kernel<<<(int)grid, 256, 0, stream>>>(
            x, ei_arr, ej_arr, weights, ab, out, N_EDGES);
        return;
    }
    hipMemsetAsync(cnt, 0, (size_t)N_NODES * sizeof(int), stream);
    {
        int grid = (N_EDGES + 255) / 256;
        hist_kernel<<<grid, 256, 0, stream>>>(ei_arr, cnt, N_EDGES);
        scan_kernel<<<1, 1024, 0, stream>>>(cnt, offs, cursor, N_NODES);
        csr_scatter_kernel<<<grid, 256, 0, stream>>>(
            ei_arr, ej_arr, weights, cursor, jsort, wsort, N_EDGES);
    }
    {
        int grid = (N_NODES * FDIM + 255) / 256;
        gather_kernel<<<grid, 256, 0, stream>>>(
            x, ab, offs, jsort, wsort, out, N_NODES);
    }
}

// Round 4
// 139.634 us; speedup vs baseline: 2.6574x; 1.1331x over previous
//
#include <hip/hip_runtime.h>
#include <hip/hip_bf16.h>
#include <hip/hip_fp16.h>

#define N_NODES 50000
#define N_EDGES 800000
#define HEADS 4
#define OUT_CH 32
#define FDIM (HEADS * OUT_CH)   // 128

// ============================================================================
// shared CSR-build kernels
// ============================================================================

__global__ void hist_kernel(const int* __restrict__ ei, int* __restrict__ cnt,
                            int n_edges) {
    int e = blockIdx.x * blockDim.x + threadIdx.x;
    if (e < n_edges) atomicAdd(&cnt[ei[e]], 1);
}

__global__ void scan1_kernel(const int* __restrict__ cnt, int* __restrict__ offs,
                             int* __restrict__ bsums, int n) {
    __shared__ int lds[256];
    int i = blockIdx.x * 256 + threadIdx.x;
    int v = (i < n) ? cnt[i] : 0;
    lds[threadIdx.x] = v;
    __syncthreads();
    for (int d = 1; d < 256; d <<= 1) {
        int t = (threadIdx.x >= d) ? lds[threadIdx.x - d] : 0;
        __syncthreads();
        lds[threadIdx.x] += t;
        __syncthreads();
    }
    if (i < n) offs[i] = lds[threadIdx.x] - v;
    if (threadIdx.x == 255) bsums[blockIdx.x] = lds[255];
}

__global__ void scan2_kernel(int* __restrict__ bsums, int* __restrict__ offs_n,
                             int nb) {
    __shared__ int lds[256];
    int v = (threadIdx.x < nb) ? bsums[threadIdx.x] : 0;
    lds[threadIdx.x] = v;
    __syncthreads();
    for (int d = 1; d < 256; d <<= 1) {
        int t = (threadIdx.x >= d) ? lds[threadIdx.x - d] : 0;
        __syncthreads();
        lds[threadIdx.x] += t;
        __syncthreads();
    }
    if (threadIdx.x < nb) bsums[threadIdx.x] = lds[threadIdx.x] - v;
    if (threadIdx.x == 255) *offs_n = lds[255];
}

__global__ void scan3_kernel(int* __restrict__ offs, int* __restrict__ cursor,
                             const int* __restrict__ bsums, int n) {
    int i = blockIdx.x * 256 + threadIdx.x;
    if (i < n) {
        int o = offs[i] + bsums[blockIdx.x];
        offs[i] = o;
        cursor[i] = o;
    }
}

// ============================================================================
// v3 path: fp16 x-table, packed 16B records, ILP'd scatter
// ============================================================================

// Fused: A/B node dots + x -> fp16 conversion. 32 threads/node.
__global__ void prep_kernel(const float4* __restrict__ x4,
                            const float* __restrict__ w,
                            float* __restrict__ Af,
                            float* __restrict__ Bf,
                            ushort4* __restrict__ xh4) {
    int gid = blockIdx.x * blockDim.x + threadIdx.x;
    int node = gid >> 5;
    int t = threadIdx.x & 31;
    int h = t >> 3;
    int q8 = t & 7;

    float4 xv = x4[node * 32 + t];

    // fp16 copy of x
    ushort4 u;
    u.x = __half_as_ushort(__float2half(xv.x));
    u.y = __half_as_ushort(__float2half(xv.y));
    u.z = __half_as_ushort(__float2half(xv.z));
    u.w = __half_as_ushort(__float2half(xv.w));
    xh4[node * 32 + t] = u;

    // per-head dot products
    const float4* w4 = (const float4*)w;
    float4 wi = w4[q8];
    float4 wj = w4[8 + q8];
    float pa = xv.x * wi.x + xv.y * wi.y + xv.z * wi.z + xv.w * wi.w;
    float pb = xv.x * wj.x + xv.y * wj.y + xv.z * wj.z + xv.w * wj.w;
    #pragma unroll
    for (int m = 4; m >= 1; m >>= 1) {
        pa += __shfl_xor(pa, m);
        pb += __shfl_xor(pb, m);
    }
    if (q8 == 0) {
        Af[node * 4 + h] = pa;
        Bf[node * 4 + h] = pb;
    }
}

// per-edge: beta4 = w_e * sigmoid(A_i + B_j) as fp16, packed with j into 16B.
// 4 edges/thread for ILP.
__global__ void scatter_rec_kernel(const int* __restrict__ ei,
                                   const int* __restrict__ ej,
                                   const float* __restrict__ weights,
                                   const float4* __restrict__ A4,
                                   const float4* __restrict__ B4,
                                   int* __restrict__ cursor,
                                   uint4* __restrict__ rec,
                                   int n_edges) {
    int base = blockIdx.x * (blockDim.x * 4) + threadIdx.x;
    #pragma unroll
    for (int u = 0; u < 4; ++u) {
        int e = base + u * 256;
        if (e >= n_edges) continue;
        int i = ei[e];
        int j = ej[e];
        float we = weights[e];
        float4 ai = A4[i];
        float4 bj = B4[j];
        float b0 = we / (1.0f + __expf(-(ai.x + bj.x)));
        float b1 = we / (1.0f + __expf(-(ai.y + bj.y)));
        float b2 = we / (1.0f + __expf(-(ai.z + bj.z)));
        float b3 = we / (1.0f + __expf(-(ai.w + bj.w)));
        uint w01 = (uint)__half_as_ushort(__float2half(b0)) |
                   ((uint)__half_as_ushort(__float2half(b1)) << 16);
        uint w23 = (uint)__half_as_ushort(__float2half(b2)) |
                   ((uint)__half_as_ushort(__float2half(b3)) << 16);
        int p = atomicAdd(&cursor[i], 1);
        uint4 r;
        r.x = (uint)j; r.y = w01; r.z = w23; r.w = 0u;
        rec[p] = r;
    }
}

// gather: 32 threads/node; one 16B broadcast record + one 8B fp16 gather per edge
__global__ void gather_rec_kernel(const ushort4* __restrict__ xh4,
                                  const int* __restrict__ offs,
                                  const uint4* __restrict__ rec,
                                  float4* __restrict__ out4) {
    int gid = blockIdx.x * blockDim.x + threadIdx.x;
    int node = gid >> 5;
    int t = threadIdx.x & 31;
    int h = t >> 3;

    int start = offs[node];
    int end = offs[node + 1];
    float4 acc = make_float4(0.f, 0.f, 0.f, 0.f);
    #pragma unroll 4
    for (int k = start; k < end; ++k) {
        uint4 r = rec[k];
        int j = (int)r.x;
        uint wrd = (h < 2) ? r.y : r.z;
        ushort hw = (h & 1) ? (ushort)(wrd >> 16) : (ushort)(wrd & 0xffffu);
        float beta = __half2float(__ushort_as_half(hw));
        ushort4 xv = xh4[j * 32 + t];
        acc.x += __half2float(__ushort_as_half(xv.x)) * beta;
        acc.y += __half2float(__ushort_as_half(xv.y)) * beta;
        acc.z += __half2float(__ushort_as_half(xv.z)) * beta;
        acc.w += __half2float(__ushort_as_half(xv.w)) * beta;
    }
    out4[node * 32 + t] = acc;
}

// ============================================================================
// v2 fallback (round-3 verified): fp32 records, separate arrays
// ============================================================================

__global__ void node_dots4_kernel(const float4* __restrict__ x4,
                                  const float* __restrict__ w,
                                  float* __restrict__ Af,
                                  float* __restrict__ Bf) {
    int gid = blockIdx.x * blockDim.x + threadIdx.x;
    int node = gid >> 5;
    int t = threadIdx.x & 31;
    int h = t >> 3;
    int q8 = t & 7;
    float4 xv = x4[node * 32 + t];
    const float4* w4 = (const float4*)w;
    float4 wi = w4[q8];
    float4 wj = w4[8 + q8];
    float pa = xv.x * wi.x + xv.y * wi.y + xv.z * wi.z + xv.w * wi.w;
    float pb = xv.x * wj.x + xv.y * wj.y + xv.z * wj.z + xv.w * wj.w;
    #pragma unroll
    for (int m = 4; m >= 1; m >>= 1) {
        pa += __shfl_xor(pa, m);
        pb += __shfl_xor(pb, m);
    }
    if (q8 == 0) {
        Af[node * 4 + h] = pa;
        Bf[node * 4 + h] = pb;
    }
}

__global__ void csr_scatter4_kernel(const int* __restrict__ ei,
                                    const int* __restrict__ ej,
                                    const float* __restrict__ weights,
                                    const float4* __restrict__ A4,
                                    const float4* __restrict__ B4,
                                    int* __restrict__ cursor,
                                    int* __restrict__ jsort,
                                    float4* __restrict__ beta4,
                                    int n_edges) {
    int e = blockIdx.x * blockDim.x + threadIdx.x;
    if (e >= n_edges) return;
    int i = ei[e];
    int j = ej[e];
    float we = weights[e];
    float4 ai = A4[i];
    float4 bj = B4[j];
    float4 bt;
    bt.x = we / (1.0f + __expf(-(ai.x + bj.x)));
    bt.y = we / (1.0f + __expf(-(ai.y + bj.y)));
    bt.z = we / (1.0f + __expf(-(ai.z + bj.z)));
    bt.w = we / (1.0f + __expf(-(ai.w + bj.w)));
    int p = atomicAdd(&cursor[i], 1);
    jsort[p] = j;
    beta4[p] = bt;
}

__global__ void gather4_kernel(const float4* __restrict__ x4,
                               const int* __restrict__ offs,
                               const int* __restrict__ jsort,
                               const float* __restrict__ betaf,
                               float4* __restrict__ out4) {
    int gid = blockIdx.x * blockDim.x + threadIdx.x;
    int node = gid >> 5;
    int t = threadIdx.x & 31;
    int h = t >> 3;
    int start = offs[node];
    int end = offs[node + 1];
    float4 acc = make_float4(0.f, 0.f, 0.f, 0.f);
    #pragma unroll 4
    for (int k = start; k < end; ++k) {
        int j = jsort[k];
        float beta = betaf[k * 4 + h];
        float4 xv = x4[j * 32 + t];
        acc.x += xv.x * beta;
        acc.y += xv.y * beta;
        acc.z += xv.z * beta;
        acc.w += xv.w * beta;
    }
    out4[node * 32 + t] = acc;
}

// ============================================================================
// v0 ultimate fallback: atomic scatter
// ============================================================================

__global__ void node_dots_kernel(const float* __restrict__ x,
                                 const float* __restrict__ w,
                                 float* __restrict__ ab,
                                 int n_nodes) {
    int gid = blockIdx.x * blockDim.x + threadIdx.x;
    int node = gid >> 7;
    int t = threadIdx.x & 127;
    if (node >= n_nodes) return;
    int h = t >> 5;
    int c = t & 31;
    float xv = x[node * FDIM + t];
    float pa = xv * w[c];
    float pb = xv * w[OUT_CH + c];
    #pragma unroll
    for (int m = 16; m >= 1; m >>= 1) {
        pa += __shfl_xor(pa, m);
        pb += __shfl_xor(pb, m);
    }
    if (c == 0) {
        ab[node * 8 + h * 2 + 0] = pa;
        ab[node * 8 + h * 2 + 1] = pb;
    }
}

__global__ void edge_scatter_kernel(const float* __restrict__ x,
                                    const int* __restrict__ ei_arr,
                                    const int* __restrict__ ej_arr,
                                    const float* __restrict__ weights,
                                    const float* __restrict__ ab,
                                    float* __restrict__ out,
                                    int n_edges) {
    int gid = blockIdx.x * blockDim.x + threadIdx.x;
    int e = gid >> 7;
    int t = threadIdx.x & 127;
    if (e >= n_edges) return;
    int h = t >> 5;
    int i = ei_arr[e];
    int j = ej_arr[e];
    float alpha = ab[i * 8 + h * 2 + 0] + ab[j * 8 + h * 2 + 1];
    float beta = weights[e] / (1.0f + __expf(-alpha));
    atomicAdd(&out[i * FDIM + t], x[j * FDIM + t] * beta);
}

// ============================================================================

extern "C" void kernel_launch(void* const* d_in, const int* in_sizes, int n_in,
                              void* d_out, int out_size, void* d_ws, size_t ws_size,
                              hipStream_t stream) {
    const float* x       = (const float*)d_in[0];
    const int*   eidx    = (const int*)d_in[1];
    const float* weights = (const float*)d_in[2];
    const float* w       = (const float*)d_in[3];
    float* out = (float*)d_out;

    const int* ei_arr = eidx;
    const int* ej_arr = eidx + N_EDGES;

    const int NB = (N_NODES + 255) / 256;  // scan blocks

    // ---- v3 workspace layout (bytes) ----
    // rec: 800000*16 = 12.8MB | xh: 6.4M halves = 12.8MB | A: 800KB | B: 800KB
    // cnt: 200KB | offs: 200KB+4 | cursor: 200KB | bsums: 1KB  => ~27.8MB
    {
        char* p = (char*)d_ws;
        uint4*   rec  = (uint4*)p;                 p += (size_t)N_EDGES * 16;
        ushort4* xh4  = (ushort4*)p;               p += (size_t)N_NODES * FDIM * 2;
        float*   Af   = (float*)p;                 p += (size_t)N_NODES * 4 * 4;
        float*   Bf   = (float*)p;                 p += (size_t)N_NODES * 4 * 4;
        int*     cnt  = (int*)p;                   p += (size_t)N_NODES * 4;
        int*     offs = (int*)p;                   p += (size_t)(N_NODES + 1) * 4;
        int*     cur  = (int*)p;                   p += (size_t)N_NODES * 4;
        int*     bsums= (int*)p;                   p += (size_t)256 * 4;
        size_t need_v3 = (size_t)(p - (char*)d_ws);

        if (ws_size >= need_v3) {
            hipMemsetAsync(cnt, 0, (size_t)N_NODES * sizeof(int), stream);
            prep_kernel<<<(N_NODES * 32 + 255) / 256, 256, 0, stream>>>(
                (const float4*)x, w, Af, Bf, xh4);
            hist_kernel<<<(N_EDGES + 255) / 256, 256, 0, stream>>>(
                ei_arr, cnt, N_EDGES);
            scan1_kernel<<<NB, 256, 0, stream>>>(cnt, offs, bsums, N_NODES);
            scan2_kernel<<<1, 256, 0, stream>>>(bsums, offs + N_NODES, NB);
            scan3_kernel<<<NB, 256, 0, stream>>>(offs, cur, bsums, N_NODES);
            scatter_rec_kernel<<<(N_EDGES + 1023) / 1024, 256, 0, stream>>>(
                ei_arr, ej_arr, weights, (const float4*)Af, (const float4*)Bf,
                cur, rec, N_EDGES);
            gather_rec_kernel<<<(N_NODES * 32 + 255) / 256, 256, 0, stream>>>(
                xh4, offs, rec, (float4*)out);
            return;
        }
    }

    // ---- v2 fallback (round-3 verified) ----
    {
        float* Af     = (float*)d_ws;
        float* Bf     = Af + N_NODES * 4;
        float* betaf  = Bf + N_NODES * 4;
        int*   jsort2 = (int*)(betaf + (size_t)N_EDGES * 4);
        int*   cnt2   = jsort2 + N_EDGES;
        int*   offs2  = cnt2 + N_NODES;
        int*   cur2   = offs2 + N_NODES + 1;
        int*   bsums  = cur2 + N_NODES;
        size_t need_v2 = (size_t)(N_NODES * 8 + N_EDGES * 5 + N_NODES * 3 + 1 + 256) * 4;

        if (ws_size >= need_v2) {
            hipMemsetAsync(cnt2, 0, (size_t)N_NODES * sizeof(int), stream);
            node_dots4_kernel<<<(N_NODES * 32 + 255) / 256, 256, 0, stream>>>(
                (const float4*)x, w, Af, Bf);
            hist_kernel<<<(N_EDGES + 255) / 256, 256, 0, stream>>>(
                ei_arr, cnt2, N_EDGES);
            scan1_kernel<<<NB, 256, 0, stream>>>(cnt2, offs2, bsums, N_NODES);
            scan2_kernel<<<1, 256, 0, stream>>>(bsums, offs2 + N_NODES, NB);
            scan3_kernel<<<NB, 256, 0, stream>>>(offs2, cur2, bsums, N_NODES);
            csr_scatter4_kernel<<<(N_EDGES + 255) / 256, 256, 0, stream>>>(
                ei_arr, ej_arr, weights, (const float4*)Af, (const float4*)Bf,
                cur2, jsort2, (float4*)betaf, N_EDGES);
            gather4_kernel<<<(N_NODES * 32 + 255) / 256, 256, 0, stream>>>(
                (const float4*)x, offs2, jsort2, betaf, (float4*)out);
            return;
        }
    }

    // ---- v0 atomic fallback ----
    {
        float* ab = (float*)d_ws;  // 1.6MB
        int grid = (N_NODES * FDIM + 255) / 256;
        node_dots_kernel<<<grid, 256, 0, stream>>>(x, w, ab, N_NODES);
        hipMemsetAsync(d_out, 0, (size_t)out_size * sizeof(float), stream);
        long long threads_total = (long long)N_EDGES * FDIM;
        long long g = (threads_total + 255) / 256;
        edge_scatter_kernel<<<(int)g, 256, 0, stream>>>(
            x, ei_arr, ej_arr, weights, ab, out, N_EDGES);
    }
}